// Round 4
// baseline (441.415 us; speedup 1.0000x reference)
//
#include <hip/hip_runtime.h>
#include <hip/hip_bf16.h>

#define NVEC   262144
#define NLIST  1024
#define DIM    64
#define NCHUNK 64          // 64 chunks x 16 centroids
#define DELTA  0.08f       // rescue threshold on encoded scores:
                           // covers 2*(1024ulp@s<256 = 0.031) + mfma ~2e-3

typedef __attribute__((ext_vector_type(8))) short bf16x8;
typedef __attribute__((ext_vector_type(4))) float f32x4;

__device__ __forceinline__ unsigned short bf_rne(float f) {
    unsigned int u = __float_as_uint(f);
    u += 0x7fffu + ((u >> 16) & 1u);
    return (unsigned short)(u >> 16);
}
__device__ __forceinline__ float bf_up(unsigned short s) {
    return __uint_as_float(((unsigned int)s) << 16);
}

// ---------------------------------------------------------------------------
// K0: csq (exact fp32), zero rescue counter, build cmat:
// chunk image 4KB: cent m row = 128 shorts; block j<8 = hi elems j*8..+7,
// j>=8 = lo elems (j-8)*8..+7, at natural position j*8.
// ---------------------------------------------------------------------------
__global__ __launch_bounds__(256) void prep_kernel(const float* __restrict__ cents,
                                                   float* __restrict__ csq,
                                                   int* __restrict__ counter,
                                                   unsigned short* __restrict__ cmat) {
    int gid = blockIdx.x * 256 + threadIdx.x;
    if (gid == 0) *counter = 0;
    if (gid < NLIST) {
        const float4* p = (const float4*)(cents + (size_t)gid * DIM);
        float s = 0.f;
#pragma unroll
        for (int i = 0; i < DIM / 4; ++i) {
            float4 t = p[i];
            s += t.x * t.x + t.y * t.y + t.z * t.z + t.w * t.w;
        }
        csq[gid] = s;
    }
    int c = gid >> 4;          // centroid 0..1023
    int j = gid & 15;          // block
    const float* src = cents + (size_t)c * DIM + (j & 7) * 8;
    unsigned short* dst = cmat + (c >> 4) * 2048 + (c & 15) * 128 + j * 8;
#pragma unroll
    for (int i = 0; i < 8; ++i) {
        float v = src[i];
        unsigned short h = bf_rne(v);
        dst[i] = (j < 8) ? h : bf_rne(v - bf_up(h));
    }
}

// ---------------------------------------------------------------------------
// K1: MFMA assign + fused gather. Wave owns 64 vecs (4 col-tiles of 16).
// A-frags loaded straight from L2 (no LDS, no barriers in K-loop).
// dot = c_hi.x_hi + c_lo.x_hi + c_hi.x_lo   (round-2 math, verified)
// Scores encoded with the centroid index in the low 10 mantissa bits ->
// top-2 tracking is pure fmin/fmax.
// ---------------------------------------------------------------------------
__global__ __launch_bounds__(256, 4) void assign_mfma(const float* __restrict__ vecs,
                                                      const float* __restrict__ cents,
                                                      const unsigned short* __restrict__ cmat,
                                                      const float* __restrict__ csq,
                                                      float* __restrict__ out,
                                                      int* __restrict__ counter,
                                                      int* __restrict__ list) {
    __shared__ int widx[256];

    const int tid  = threadIdx.x;
    const int lane = tid & 63;
    const int wave = tid >> 6;
    const int n    = lane & 15;   // vec-in-tile (B), cent-in-chunk (A)
    const int q    = lane >> 4;

    const int vbase = blockIdx.x * 256 + wave * 64;

    // B fragments: x_hi/x_lo, 2 K-blocks of 32, 4 tiles. 64 VGPRs.
    bf16x8 xhi[4][2], xlo[4][2];
#pragma unroll
    for (int t = 0; t < 4; ++t) {
        const float* vp = vecs + (size_t)(vbase + t * 16 + n) * DIM + q * 8;
#pragma unroll
        for (int kb = 0; kb < 2; ++kb) {
            float4 f0 = *(const float4*)(vp + kb * 32);
            float4 f1 = *(const float4*)(vp + kb * 32 + 4);
            float vv[8] = {f0.x, f0.y, f0.z, f0.w, f1.x, f1.y, f1.z, f1.w};
#pragma unroll
            for (int i = 0; i < 8; ++i) {
                unsigned short h = bf_rne(vv[i]);
                xhi[t][kb][i] = (short)h;
                xlo[t][kb][i] = (short)bf_rne(vv[i] - bf_up(h));
            }
        }
    }

    const float FMAX = 3.0e38f;
    float min1[4] = {FMAX, FMAX, FMAX, FMAX};
    float min2[4] = {FMAX, FMAX, FMAX, FMAX};

    for (int c = 0; c < NCHUNK; ++c) {
        const unsigned short* Cb = cmat + c * 2048 + n * 128 + q * 8;
        bf16x8 a0 = *(const bf16x8*)(Cb);        // hi, k 0..31
        bf16x8 a1 = *(const bf16x8*)(Cb + 32);   // hi, k 32..63
        bf16x8 a2 = *(const bf16x8*)(Cb + 64);   // lo, k 0..31
        bf16x8 a3 = *(const bf16x8*)(Cb + 96);   // lo, k 32..63
        float4 cs = *(const float4*)(csq + c * 16 + q * 4);

        f32x4 acc[4];
#pragma unroll
        for (int t = 0; t < 4; ++t) acc[t] = (f32x4){0.f, 0.f, 0.f, 0.f};
        // dot = c_hi.x_hi + c_lo.x_hi + c_hi.x_lo  (4 indep chains)
#pragma unroll
        for (int t = 0; t < 4; ++t) acc[t] = __builtin_amdgcn_mfma_f32_16x16x32_bf16(a0, xhi[t][0], acc[t], 0, 0, 0);
#pragma unroll
        for (int t = 0; t < 4; ++t) acc[t] = __builtin_amdgcn_mfma_f32_16x16x32_bf16(a1, xhi[t][1], acc[t], 0, 0, 0);
#pragma unroll
        for (int t = 0; t < 4; ++t) acc[t] = __builtin_amdgcn_mfma_f32_16x16x32_bf16(a2, xhi[t][0], acc[t], 0, 0, 0);
#pragma unroll
        for (int t = 0; t < 4; ++t) acc[t] = __builtin_amdgcn_mfma_f32_16x16x32_bf16(a3, xhi[t][1], acc[t], 0, 0, 0);
#pragma unroll
        for (int t = 0; t < 4; ++t) acc[t] = __builtin_amdgcn_mfma_f32_16x16x32_bf16(a0, xlo[t][0], acc[t], 0, 0, 0);
#pragma unroll
        for (int t = 0; t < 4; ++t) acc[t] = __builtin_amdgcn_mfma_f32_16x16x32_bf16(a1, xlo[t][1], acc[t], 0, 0, 0);

        const int bg = c * 16 + q * 4;          // + r = centroid index, 10 bits
        float csr[4] = {cs.x, cs.y, cs.z, cs.w};
#pragma unroll
        for (int t = 0; t < 4; ++t) {
#pragma unroll
            for (int r = 0; r < 4; ++r) {
                float s = fmaf(-2.0f, acc[t][r], csr[r]);
                unsigned eu = (__float_as_uint(s) & 0xFFFFFC00u) | (unsigned)(bg + r);
                float e = __uint_as_float(eu);
                min2[t] = fminf(min2[t], fmaxf(min1[t], e));   // old min1!
                min1[t] = fminf(min1[t], e);
            }
        }
    }

    // merge top-2 across the 4 quads of each vec-column
#pragma unroll
    for (int t = 0; t < 4; ++t) {
#pragma unroll
        for (int off = 16; off <= 32; off <<= 1) {
            float o1 = __shfl_xor(min1[t], off, 64);
            float o2 = __shfl_xor(min2[t], off, 64);
            float nm2 = fminf(fmaxf(min1[t], o1), fminf(min2[t], o2));
            min1[t] = fminf(min1[t], o1);
            min2[t] = nm2;
        }
        if (lane < 16) {
            int slot = wave * 64 + t * 16 + lane;
            widx[slot] = (int)(__float_as_uint(min1[t]) & 1023u);
            if (min2[t] - min1[t] < DELTA) {
                int pos = atomicAdd(counter, 1);
                list[pos] = blockIdx.x * 256 + slot;
            }
        }
    }

    __syncthreads();
    // fused gather: 256 rows x 64 floats, fully coalesced float4 stores
    const size_t obase = (size_t)blockIdx.x * 256;
#pragma unroll
    for (int g = 0; g < 16; ++g) {
        int row = g * 16 + (tid >> 4);
        int e = tid & 15;
        int idx = widx[row];
        ((float4*)out)[(obase + row) * 16 + e] =
            ((const float4*)cents)[(size_t)idx * 16 + e];
    }
}

// ---------------------------------------------------------------------------
// K2: exact fp32 rescue, one wave per flagged row; writes the out row.
// ---------------------------------------------------------------------------
__global__ __launch_bounds__(256) void rescue_kernel(const float* __restrict__ vecs,
                                                     const float* __restrict__ cents,
                                                     const float* __restrict__ csq,
                                                     const int* __restrict__ counter,
                                                     const int* __restrict__ list,
                                                     float* __restrict__ out) {
    int nflag = *counter;
    int gwave = (blockIdx.x * 256 + threadIdx.x) >> 6;
    int lane  = threadIdx.x & 63;
    int nw    = gridDim.x * 4;
    for (int i = gwave; i < nflag; i += nw) {
        int v = list[i];
        float x[DIM];
        const float4* vp = (const float4*)(vecs + (size_t)v * DIM);
#pragma unroll
        for (int k = 0; k < DIM / 4; ++k) {
            float4 t = vp[k];
            x[4 * k] = t.x; x[4 * k + 1] = t.y; x[4 * k + 2] = t.z; x[4 * k + 3] = t.w;
        }
        float best = 3.0e38f; int bi = 0;
        for (int j = 0; j < 16; ++j) {
            int cc = j * 64 + lane;                 // ascending per lane
            const float* cp = cents + (size_t)cc * DIM;
            float a0 = 0.f, a1 = 0.f, a2 = 0.f, a3 = 0.f;
#pragma unroll
            for (int k = 0; k < DIM; k += 4) {
                a0 = fmaf(x[k + 0], cp[k + 0], a0);
                a1 = fmaf(x[k + 1], cp[k + 1], a1);
                a2 = fmaf(x[k + 2], cp[k + 2], a2);
                a3 = fmaf(x[k + 3], cp[k + 3], a3);
            }
            float dot = (a0 + a1) + (a2 + a3);
            float s = fmaf(-2.f, dot, csq[cc]);
            if (s < best) { best = s; bi = cc; }
        }
        for (int off = 1; off < 64; off <<= 1) {
            float os = __shfl_xor(best, off, 64);
            int   oi = __shfl_xor(bi, off, 64);
            if (os < best || (os == best && oi < bi)) { best = os; bi = oi; }
        }
        out[(size_t)v * DIM + lane] = cents[(size_t)bi * DIM + lane];
    }
}

extern "C" void kernel_launch(void* const* d_in, const int* in_sizes, int n_in,
                              void* d_out, int out_size, void* d_ws, size_t ws_size,
                              hipStream_t stream) {
    const float* vecs  = (const float*)d_in[0];
    const float* cents = (const float*)d_in[1];
    float*       out   = (float*)d_out;

    // ws layout (16B aligned)
    float*          csq     = (float*)d_ws;                                 //   4096 B
    int*            counter = (int*)((char*)d_ws + 4096);                   //    256 B
    int*            list    = (int*)((char*)d_ws + 8192);                   //   1 MB (cap NVEC)
    unsigned short* cmat    = (unsigned short*)((char*)d_ws + 8192 + 1048576); // 256 KB

    prep_kernel<<<dim3(64), dim3(256), 0, stream>>>(cents, csq, counter, cmat);
    assign_mfma<<<dim3(1024), dim3(256), 0, stream>>>(vecs, cents, cmat, csq, out, counter, list);
    rescue_kernel<<<dim3(256), dim3(256), 0, stream>>>(vecs, cents, csq, counter, list, out);
}

// Round 5
// 384.459 us; speedup vs baseline: 1.1481x; 1.1481x over previous
//
#include <hip/hip_runtime.h>
#include <hip/hip_bf16.h>

#define NVEC   262144
#define NLIST  1024
#define DIM    64
#define NCHUNK 64          // 64 chunks x 16 centroids
#define GRP    4           // chunks staged per barrier group
#define NGRP   (NCHUNK / GRP)
#define DELTA  0.08f       // rescue threshold on encoded scores

typedef __attribute__((ext_vector_type(8))) short bf16x8;
typedef __attribute__((ext_vector_type(4))) float f32x4;

__device__ __forceinline__ unsigned short bf_rne(float f) {
    unsigned int u = __float_as_uint(f);
    u += 0x7fffu + ((u >> 16) & 1u);
    return (unsigned short)(u >> 16);
}
__device__ __forceinline__ float bf_up(unsigned short s) {
    return __uint_as_float(((unsigned int)s) << 16);
}

// ---------------------------------------------------------------------------
// K0: csq (exact fp32), zero rescue counter, build cmat in FRAG ORDER:
// chunk ch = 4KB image laid out as [read r 0..3][lane l=q*16+n][8 shorts]
//   r=0: hi elems q*8..+7   r=1: hi elems 32+q*8..+7
//   r=2: lo elems q*8..+7   r=3: lo elems 32+q*8..+7      (cent = ch*16+n)
// => assign's ds_read_b128 for read r: lane l reads ch*4096 + r*1024 + l*16,
//    i.e. 64 lanes read a contiguous 1KB — minimal (free) bank aliasing.
//    Also identical order to global_load_lds staging (base + lane*16).
// ---------------------------------------------------------------------------
__global__ __launch_bounds__(256) void prep_kernel(const float* __restrict__ cents,
                                                   float* __restrict__ csq,
                                                   int* __restrict__ counter,
                                                   unsigned short* __restrict__ cmat) {
    int gid = blockIdx.x * 256 + threadIdx.x;     // 0..16383
    if (gid == 0) *counter = 0;
    if (gid < NLIST) {
        const float4* p = (const float4*)(cents + (size_t)gid * DIM);
        float s = 0.f;
#pragma unroll
        for (int i = 0; i < DIM / 4; ++i) {
            float4 t = p[i];
            s += t.x * t.x + t.y * t.y + t.z * t.z + t.w * t.w;
        }
        csq[gid] = s;
    }
    int c   = gid >> 4;        // centroid 0..1023
    int sub = gid & 15;        // r*4 + q
    int r   = sub >> 2;
    int qq  = sub & 3;
    const float* src = cents + (size_t)c * DIM + (r & 1) * 32 + qq * 8;
    unsigned short* dst = cmat + (c >> 4) * 2048 + r * 512 + (qq * 16 + (c & 15)) * 8;
    bool hi = (r < 2);
#pragma unroll
    for (int i = 0; i < 8; ++i) {
        float v = src[i];
        unsigned short h = bf_rne(v);
        dst[i] = hi ? h : bf_rne(v - bf_up(h));
    }
}

// ---------------------------------------------------------------------------
// K1: MFMA assign + fused gather. Wave owns 64 vecs (4 col-tiles of 16).
// Double-buffered global_load_lds staging, 4 chunks (96 MFMA) per barrier.
// dot = c_hi.x_hi + c_lo.x_hi + c_hi.x_lo   (round-2 verified math)
// Scores carry the centroid index in the low 10 mantissa bits -> top-2 is
// pure fmin/fmax; close top-2 gaps (< DELTA) re-solved exactly by rescue.
// ---------------------------------------------------------------------------
__global__ __launch_bounds__(256, 4) void assign_mfma(const float* __restrict__ vecs,
                                                      const float* __restrict__ cents,
                                                      const unsigned short* __restrict__ cmat,
                                                      const float* __restrict__ csq_g,
                                                      float* __restrict__ out,
                                                      int* __restrict__ counter,
                                                      int* __restrict__ list) {
    __shared__ __align__(16) float csq_lds[NLIST];                    //  4 KB
    __shared__ __align__(16) unsigned short chunkbuf[2][GRP * 2048];  // 32 KB
    __shared__ int widx[256];                                         //  1 KB

    const int tid  = threadIdx.x;
    const int lane = tid & 63;
    const int wave = tid >> 6;
    const int n    = lane & 15;   // vec-in-tile (B / D-col), cent (A-row)
    const int q    = lane >> 4;   // k-group; D-row group

    ((float4*)csq_lds)[tid] = ((const float4*)csq_g)[tid];

    const int vbase = blockIdx.x * 256 + wave * 64;

    // B fragments: x_hi/x_lo, 2 K-blocks of 32, 4 tiles. 64 VGPRs.
    bf16x8 xhi[4][2], xlo[4][2];
#pragma unroll
    for (int t = 0; t < 4; ++t) {
        const float* vp = vecs + (size_t)(vbase + t * 16 + n) * DIM + q * 8;
#pragma unroll
        for (int kb = 0; kb < 2; ++kb) {
            float4 f0 = *(const float4*)(vp + kb * 32);
            float4 f1 = *(const float4*)(vp + kb * 32 + 4);
            float vv[8] = {f0.x, f0.y, f0.z, f0.w, f1.x, f1.y, f1.z, f1.w};
#pragma unroll
            for (int i = 0; i < 8; ++i) {
                unsigned short h = bf_rne(vv[i]);
                xhi[t][kb][i] = (short)h;
                xlo[t][kb][i] = (short)bf_rne(vv[i] - bf_up(h));
            }
        }
    }

    // stage group 0: wave w stages chunk w (4 KB = 4 insts of 64 lanes x 16B)
#pragma unroll
    for (int p = 0; p < 4; ++p) {
        const unsigned short* g = cmat + wave * 2048 + p * 512 + lane * 8;
        __builtin_amdgcn_global_load_lds(
            (const __attribute__((address_space(1))) void*)g,
            (__attribute__((address_space(3))) void*)(&chunkbuf[0][wave * 2048 + p * 512]),
            16, 0, 0);
    }

    const float FMAX = 3.0e38f;
    float min1[4] = {FMAX, FMAX, FMAX, FMAX};
    float min2[4] = {FMAX, FMAX, FMAX, FMAX};

    for (int g = 0; g < NGRP; ++g) {
        __syncthreads();   // publishes buf[g&1]; drains in-flight staging
        if (g + 1 < NGRP) {
#pragma unroll
            for (int p = 0; p < 4; ++p) {
                const unsigned short* gp = cmat + ((g + 1) * GRP + wave) * 2048
                                         + p * 512 + lane * 8;
                __builtin_amdgcn_global_load_lds(
                    (const __attribute__((address_space(1))) void*)gp,
                    (__attribute__((address_space(3))) void*)(&chunkbuf[(g + 1) & 1][wave * 2048 + p * 512]),
                    16, 0, 0);
            }
        }
        const unsigned short* B = chunkbuf[g & 1];
#pragma unroll
        for (int cc = 0; cc < GRP; ++cc) {
            const int c = g * GRP + cc;
            const unsigned short* Cb = B + cc * 2048 + lane * 8;
            bf16x8 a0 = *(const bf16x8*)(Cb);          // hi, k 0..31
            bf16x8 a1 = *(const bf16x8*)(Cb + 512);    // hi, k 32..63
            bf16x8 a2 = *(const bf16x8*)(Cb + 1024);   // lo, k 0..31
            bf16x8 a3 = *(const bf16x8*)(Cb + 1536);   // lo, k 32..63
            float4 cs = *(const float4*)(csq_lds + c * 16 + q * 4);

            f32x4 acc[4];
#pragma unroll
            for (int t = 0; t < 4; ++t) acc[t] = (f32x4){0.f, 0.f, 0.f, 0.f};
            // dot = c_hi.x_hi + c_lo.x_hi + c_hi.x_lo
#pragma unroll
            for (int t = 0; t < 4; ++t) acc[t] = __builtin_amdgcn_mfma_f32_16x16x32_bf16(a0, xhi[t][0], acc[t], 0, 0, 0);
#pragma unroll
            for (int t = 0; t < 4; ++t) acc[t] = __builtin_amdgcn_mfma_f32_16x16x32_bf16(a1, xhi[t][1], acc[t], 0, 0, 0);
#pragma unroll
            for (int t = 0; t < 4; ++t) acc[t] = __builtin_amdgcn_mfma_f32_16x16x32_bf16(a2, xhi[t][0], acc[t], 0, 0, 0);
#pragma unroll
            for (int t = 0; t < 4; ++t) acc[t] = __builtin_amdgcn_mfma_f32_16x16x32_bf16(a3, xhi[t][1], acc[t], 0, 0, 0);
#pragma unroll
            for (int t = 0; t < 4; ++t) acc[t] = __builtin_amdgcn_mfma_f32_16x16x32_bf16(a0, xlo[t][0], acc[t], 0, 0, 0);
#pragma unroll
            for (int t = 0; t < 4; ++t) acc[t] = __builtin_amdgcn_mfma_f32_16x16x32_bf16(a1, xlo[t][1], acc[t], 0, 0, 0);

            const int bg = c * 16 + q * 4;      // + r = centroid index (10 bits)
            float csr[4] = {cs.x, cs.y, cs.z, cs.w};
#pragma unroll
            for (int t = 0; t < 4; ++t) {
#pragma unroll
                for (int r = 0; r < 4; ++r) {
                    float s = fmaf(-2.0f, acc[t][r], csr[r]);
                    unsigned eu = (__float_as_uint(s) & 0xFFFFFC00u) | (unsigned)(bg + r);
                    float e = __uint_as_float(eu);
                    min2[t] = fminf(min2[t], fmaxf(min1[t], e));   // old min1!
                    min1[t] = fminf(min1[t], e);
                }
            }
        }
    }

    // merge top-2 across the 4 quads of each vec-column
#pragma unroll
    for (int t = 0; t < 4; ++t) {
#pragma unroll
        for (int off = 16; off <= 32; off <<= 1) {
            float o1 = __shfl_xor(min1[t], off, 64);
            float o2 = __shfl_xor(min2[t], off, 64);
            float nm2 = fminf(fmaxf(min1[t], o1), fminf(min2[t], o2));
            min1[t] = fminf(min1[t], o1);
            min2[t] = nm2;
        }
        if (lane < 16) {
            int slot = wave * 64 + t * 16 + lane;
            widx[slot] = (int)(__float_as_uint(min1[t]) & 1023u);
            if (min2[t] - min1[t] < DELTA) {
                int pos = atomicAdd(counter, 1);
                list[pos] = blockIdx.x * 256 + slot;
            }
        }
    }

    __syncthreads();
    // fused gather: 256 rows x 64 floats, fully coalesced float4 stores
    const size_t obase = (size_t)blockIdx.x * 256;
#pragma unroll
    for (int g = 0; g < 16; ++g) {
        int row = g * 16 + (tid >> 4);
        int e = tid & 15;
        int idx = widx[row];
        ((float4*)out)[(obase + row) * 16 + e] =
            ((const float4*)cents)[(size_t)idx * 16 + e];
    }
}

// ---------------------------------------------------------------------------
// K2: exact fp32 rescue, one wave per flagged row; writes the out row.
// ---------------------------------------------------------------------------
__global__ __launch_bounds__(256) void rescue_kernel(const float* __restrict__ vecs,
                                                     const float* __restrict__ cents,
                                                     const float* __restrict__ csq,
                                                     const int* __restrict__ counter,
                                                     const int* __restrict__ list,
                                                     float* __restrict__ out) {
    int nflag = *counter;
    int gwave = (blockIdx.x * 256 + threadIdx.x) >> 6;
    int lane  = threadIdx.x & 63;
    int nw    = gridDim.x * 4;
    for (int i = gwave; i < nflag; i += nw) {
        int v = list[i];
        float x[DIM];
        const float4* vp = (const float4*)(vecs + (size_t)v * DIM);
#pragma unroll
        for (int k = 0; k < DIM / 4; ++k) {
            float4 t = vp[k];
            x[4 * k] = t.x; x[4 * k + 1] = t.y; x[4 * k + 2] = t.z; x[4 * k + 3] = t.w;
        }
        float best = 3.0e38f; int bi = 0;
        for (int j = 0; j < 16; ++j) {
            int cc = j * 64 + lane;                 // ascending per lane
            const float* cp = cents + (size_t)cc * DIM;
            float a0 = 0.f, a1 = 0.f, a2 = 0.f, a3 = 0.f;
#pragma unroll
            for (int k = 0; k < DIM; k += 4) {
                a0 = fmaf(x[k + 0], cp[k + 0], a0);
                a1 = fmaf(x[k + 1], cp[k + 1], a1);
                a2 = fmaf(x[k + 2], cp[k + 2], a2);
                a3 = fmaf(x[k + 3], cp[k + 3], a3);
            }
            float dot = (a0 + a1) + (a2 + a3);
            float s = fmaf(-2.f, dot, csq[cc]);
            if (s < best) { best = s; bi = cc; }
        }
        for (int off = 1; off < 64; off <<= 1) {
            float os = __shfl_xor(best, off, 64);
            int   oi = __shfl_xor(bi, off, 64);
            if (os < best || (os == best && oi < bi)) { best = os; bi = oi; }
        }
        out[(size_t)v * DIM + lane] = cents[(size_t)bi * DIM + lane];
    }
}

extern "C" void kernel_launch(void* const* d_in, const int* in_sizes, int n_in,
                              void* d_out, int out_size, void* d_ws, size_t ws_size,
                              hipStream_t stream) {
    const float* vecs  = (const float*)d_in[0];
    const float* cents = (const float*)d_in[1];
    float*       out   = (float*)d_out;

    // ws layout (16B aligned)
    float*          csq     = (float*)d_ws;                                    //   4096 B
    int*            counter = (int*)((char*)d_ws + 4096);                      //    256 B
    int*            list    = (int*)((char*)d_ws + 8192);                      //   1 MB
    unsigned short* cmat    = (unsigned short*)((char*)d_ws + 8192 + 1048576); // 256 KB

    prep_kernel<<<dim3(64), dim3(256), 0, stream>>>(cents, csq, counter, cmat);
    assign_mfma<<<dim3(1024), dim3(256), 0, stream>>>(vecs, cents, cmat, csq, out, counter, list);
    rescue_kernel<<<dim3(256), dim3(256), 0, stream>>>(vecs, cents, csq, counter, list, out);
}

// Round 6
// 267.530 us; speedup vs baseline: 1.6500x; 1.4371x over previous
//
#include <hip/hip_runtime.h>
#include <hip/hip_bf16.h>

#define NVEC   262144
#define NLIST  1024
#define DIM    64
#define NCHUNK 64          // 64 chunks x 16 centroids
#define GRP    4           // chunks staged per barrier group
#define NGRP   (NCHUNK / GRP)
#define SCALE  4096.0f     // int score quantum = 1/4096
#define DELTA_INT 96       // gap threshold in quanta (= 0.0234 in d^2)

typedef __attribute__((ext_vector_type(8))) short bf16x8;
typedef __attribute__((ext_vector_type(4))) float f32x4;

__device__ __forceinline__ unsigned short bf_rne(float f) {
    unsigned int u = __float_as_uint(f);
    u += 0x7fffu + ((u >> 16) & 1u);
    return (unsigned short)(u >> 16);
}
__device__ __forceinline__ float bf_up(unsigned short s) {
    return __uint_as_float(((unsigned int)s) << 16);
}

// ---------------------------------------------------------------------------
// K0: csq + csq*4096 (exact fp32), zero counter, build cmat in FRAG ORDER:
// chunk ch = 4KB image [read r 0..3][lane l][8 shorts]:
//   r=0: hi k 0..31   r=1: hi k 32..63   r=2: lo k 0..31   r=3: lo k 32..63
// assign's ds_read_b128 for read r: lane l reads ch*4096+r*1024+l*16 —
// 64 lanes read a contiguous 1KB (free 2-way aliasing only), and staging
// order matches global_load_lds (base + lane*16).
// ---------------------------------------------------------------------------
__global__ __launch_bounds__(256) void prep_kernel(const float* __restrict__ cents,
                                                   float* __restrict__ csq,
                                                   float* __restrict__ csq4k,
                                                   int* __restrict__ counter,
                                                   unsigned short* __restrict__ cmat) {
    int gid = blockIdx.x * 256 + threadIdx.x;     // 0..16383
    if (gid == 0) *counter = 0;
    if (gid < NLIST) {
        const float4* p = (const float4*)(cents + (size_t)gid * DIM);
        float s = 0.f;
#pragma unroll
        for (int i = 0; i < DIM / 4; ++i) {
            float4 t = p[i];
            s += t.x * t.x + t.y * t.y + t.z * t.z + t.w * t.w;
        }
        csq[gid] = s;
        csq4k[gid] = s * SCALE;
    }
    int c   = gid >> 4;        // centroid 0..1023
    int sub = gid & 15;        // r*4 + q
    int r   = sub >> 2;
    int qq  = sub & 3;
    const float* src = cents + (size_t)c * DIM + (r & 1) * 32 + qq * 8;
    unsigned short* dst = cmat + (c >> 4) * 2048 + r * 512 + (qq * 16 + (c & 15)) * 8;
    bool hi = (r < 2);
#pragma unroll
    for (int i = 0; i < 8; ++i) {
        float v = src[i];
        unsigned short h = bf_rne(v);
        dst[i] = hi ? h : bf_rne(v - bf_up(h));
    }
}

// ---------------------------------------------------------------------------
// K1: MFMA assign + fused gather. Wave owns 64 vecs (4 col-tiles of 16).
// Double-buffered global_load_lds staging, 4 chunks (96 MFMA) per barrier.
// dot = c_hi.x_hi + c_lo.x_hi + c_hi.x_lo   (round-2 verified math)
// Scores as ints: q = trunc(4096*d2_approx), e = (q<<10)|cent -> top-2 via
// v_min/max_i32; quantum 2.4e-4, so DELTA covers mfma err with 2x margin.
// ---------------------------------------------------------------------------
__global__ __launch_bounds__(256, 4) void assign_mfma(const float* __restrict__ vecs,
                                                      const float* __restrict__ cents,
                                                      const unsigned short* __restrict__ cmat,
                                                      const float* __restrict__ csq4k_g,
                                                      float* __restrict__ out,
                                                      int* __restrict__ counter,
                                                      int* __restrict__ list) {
    __shared__ __align__(16) float csq_lds[NLIST];                    //  4 KB (scaled)
    __shared__ __align__(16) unsigned short chunkbuf[2][GRP * 2048];  // 32 KB
    __shared__ int widx[256];                                         //  1 KB

    const int tid  = threadIdx.x;
    const int lane = tid & 63;
    const int wave = tid >> 6;
    const int n    = lane & 15;   // vec-in-tile (B / D-col), cent (A-row)
    const int q    = lane >> 4;   // k-group; D-row group

    ((float4*)csq_lds)[tid] = ((const float4*)csq4k_g)[tid];

    const int vbase = blockIdx.x * 256 + wave * 64;

    // B fragments: x_hi/x_lo, 2 K-blocks of 32, 4 tiles. 64 VGPRs.
    bf16x8 xhi[4][2], xlo[4][2];
#pragma unroll
    for (int t = 0; t < 4; ++t) {
        const float* vp = vecs + (size_t)(vbase + t * 16 + n) * DIM + q * 8;
#pragma unroll
        for (int kb = 0; kb < 2; ++kb) {
            float4 f0 = *(const float4*)(vp + kb * 32);
            float4 f1 = *(const float4*)(vp + kb * 32 + 4);
            float vv[8] = {f0.x, f0.y, f0.z, f0.w, f1.x, f1.y, f1.z, f1.w};
#pragma unroll
            for (int i = 0; i < 8; ++i) {
                unsigned short h = bf_rne(vv[i]);
                xhi[t][kb][i] = (short)h;
                xlo[t][kb][i] = (short)bf_rne(vv[i] - bf_up(h));
            }
        }
    }

    // stage group 0: wave w stages chunk w (4 KB = 4 insts of 64 lanes x 16B)
#pragma unroll
    for (int p = 0; p < 4; ++p) {
        const unsigned short* g = cmat + wave * 2048 + p * 512 + lane * 8;
        __builtin_amdgcn_global_load_lds(
            (const __attribute__((address_space(1))) void*)g,
            (__attribute__((address_space(3))) void*)(&chunkbuf[0][wave * 2048 + p * 512]),
            16, 0, 0);
    }

    const int IMAX = 0x7FFFFFFF;
    int min1[4] = {IMAX, IMAX, IMAX, IMAX};
    int min2[4] = {IMAX, IMAX, IMAX, IMAX};

    for (int g = 0; g < NGRP; ++g) {
        __syncthreads();   // publishes buf[g&1]; drains in-flight staging
        if (g + 1 < NGRP) {
#pragma unroll
            for (int p = 0; p < 4; ++p) {
                const unsigned short* gp = cmat + ((g + 1) * GRP + wave) * 2048
                                         + p * 512 + lane * 8;
                __builtin_amdgcn_global_load_lds(
                    (const __attribute__((address_space(1))) void*)gp,
                    (__attribute__((address_space(3))) void*)(&chunkbuf[(g + 1) & 1][wave * 2048 + p * 512]),
                    16, 0, 0);
            }
        }
        const unsigned short* B = chunkbuf[g & 1];
#pragma unroll
        for (int cc = 0; cc < GRP; ++cc) {
            const int c = g * GRP + cc;
            const unsigned short* Cb = B + cc * 2048 + lane * 8;
            bf16x8 a0 = *(const bf16x8*)(Cb);          // hi, k 0..31
            bf16x8 a1 = *(const bf16x8*)(Cb + 512);    // hi, k 32..63
            bf16x8 a2 = *(const bf16x8*)(Cb + 1024);   // lo, k 0..31
            bf16x8 a3 = *(const bf16x8*)(Cb + 1536);   // lo, k 32..63
            float4 cs = *(const float4*)(csq_lds + c * 16 + q * 4);

            f32x4 acc[4];
#pragma unroll
            for (int t = 0; t < 4; ++t) acc[t] = (f32x4){0.f, 0.f, 0.f, 0.f};
            // dot = c_hi.x_hi + c_lo.x_hi + c_hi.x_lo
#pragma unroll
            for (int t = 0; t < 4; ++t) acc[t] = __builtin_amdgcn_mfma_f32_16x16x32_bf16(a0, xhi[t][0], acc[t], 0, 0, 0);
#pragma unroll
            for (int t = 0; t < 4; ++t) acc[t] = __builtin_amdgcn_mfma_f32_16x16x32_bf16(a1, xhi[t][1], acc[t], 0, 0, 0);
#pragma unroll
            for (int t = 0; t < 4; ++t) acc[t] = __builtin_amdgcn_mfma_f32_16x16x32_bf16(a2, xhi[t][0], acc[t], 0, 0, 0);
#pragma unroll
            for (int t = 0; t < 4; ++t) acc[t] = __builtin_amdgcn_mfma_f32_16x16x32_bf16(a3, xhi[t][1], acc[t], 0, 0, 0);
#pragma unroll
            for (int t = 0; t < 4; ++t) acc[t] = __builtin_amdgcn_mfma_f32_16x16x32_bf16(a0, xlo[t][0], acc[t], 0, 0, 0);
#pragma unroll
            for (int t = 0; t < 4; ++t) acc[t] = __builtin_amdgcn_mfma_f32_16x16x32_bf16(a1, xlo[t][1], acc[t], 0, 0, 0);

            const int bg = c * 16 + q * 4;      // + r = centroid index (10 bits)
            float csr[4] = {cs.x, cs.y, cs.z, cs.w};
#pragma unroll
            for (int t = 0; t < 4; ++t) {
#pragma unroll
                for (int r = 0; r < 4; ++r) {
                    float s = fmaf(-2.0f * SCALE, acc[t][r], csr[r]);
                    int qi = (int)s;            // trunc toward 0, monotone
                    int e = (int)((((unsigned)qi) << 10) | (unsigned)(bg + r));
                    min2[t] = min(min2[t], max(min1[t], e));   // old min1!
                    min1[t] = min(min1[t], e);
                }
            }
        }
    }

    // merge top-2 across the 4 quads of each vec-column
#pragma unroll
    for (int t = 0; t < 4; ++t) {
#pragma unroll
        for (int off = 16; off <= 32; off <<= 1) {
            int o1 = __shfl_xor(min1[t], off, 64);
            int o2 = __shfl_xor(min2[t], off, 64);
            int nm2 = min(max(min1[t], o1), min(min2[t], o2));
            min1[t] = min(min1[t], o1);
            min2[t] = nm2;
        }
        if (lane < 16) {
            int slot = wave * 64 + t * 16 + lane;
            widx[slot] = min1[t] & 1023;
            if ((min2[t] >> 10) - (min1[t] >> 10) < DELTA_INT) {
                int pos = atomicAdd(counter, 1);
                list[pos] = blockIdx.x * 256 + slot;
            }
        }
    }

    __syncthreads();
    // fused gather: 256 rows x 64 floats, fully coalesced float4 stores
    const size_t obase = (size_t)blockIdx.x * 256;
#pragma unroll
    for (int g = 0; g < 16; ++g) {
        int row = g * 16 + (tid >> 4);
        int e = tid & 15;
        int idx = widx[row];
        ((float4*)out)[(obase + row) * 16 + e] =
            ((const float4*)cents)[(size_t)idx * 16 + e];
    }
}

// ---------------------------------------------------------------------------
// K2: exact fp32 rescue v2 — block per PAIR of flagged rows; 256 threads,
// thread t dots centroids {t, 256+t, 512+t, 768+t} for both rows (cent row
// loaded once). Exact round-0 fmaf chain; lexicographic (s, idx) reduction.
// ---------------------------------------------------------------------------
__global__ __launch_bounds__(256) void rescue_kernel(const float* __restrict__ vecs,
                                                     const float* __restrict__ cents,
                                                     const float* __restrict__ csq,
                                                     const int* __restrict__ counter,
                                                     const int* __restrict__ list,
                                                     float* __restrict__ out) {
    __shared__ __align__(16) float xs[2][DIM];
    __shared__ float rbest[8];
    __shared__ int   rbi[8];
    __shared__ int   fin[2];

    const int nflag = *counter;
    const int tid  = threadIdx.x;
    const int lane = tid & 63;
    const int wv   = tid >> 6;

    for (int i = blockIdx.x * 2; i < nflag; i += gridDim.x * 2) {
        int v0 = list[i];
        int v1 = (i + 1 < nflag) ? list[i + 1] : v0;
        __syncthreads();
        if (tid < 16)       ((float4*)xs[0])[tid]      = ((const float4*)(vecs + (size_t)v0 * DIM))[tid];
        else if (tid < 32)  ((float4*)xs[1])[tid - 16] = ((const float4*)(vecs + (size_t)v1 * DIM))[tid - 16];
        __syncthreads();

        float b0 = 3.0e38f, b1 = 3.0e38f;
        int   i0 = 0, i1 = 0;
#pragma unroll
        for (int j = 0; j < 4; ++j) {
            int c = j * 256 + tid;              // ascending per thread
            const float4* cp = (const float4*)(cents + (size_t)c * DIM);
            float a0 = 0.f, a1 = 0.f, a2 = 0.f, a3 = 0.f;
            float c0 = 0.f, c1 = 0.f, c2 = 0.f, c3 = 0.f;
#pragma unroll
            for (int k = 0; k < DIM / 4; ++k) {
                float4 cv = cp[k];
                float4 x0 = ((const float4*)xs[0])[k];
                float4 x1 = ((const float4*)xs[1])[k];
                a0 = fmaf(x0.x, cv.x, a0);
                a1 = fmaf(x0.y, cv.y, a1);
                a2 = fmaf(x0.z, cv.z, a2);
                a3 = fmaf(x0.w, cv.w, a3);
                c0 = fmaf(x1.x, cv.x, c0);
                c1 = fmaf(x1.y, cv.y, c1);
                c2 = fmaf(x1.z, cv.z, c2);
                c3 = fmaf(x1.w, cv.w, c3);
            }
            float d0 = (a0 + a1) + (a2 + a3);
            float d1 = (c0 + c1) + (c2 + c3);
            float s0 = fmaf(-2.f, d0, csq[c]);
            float s1 = fmaf(-2.f, d1, csq[c]);
            if (s0 < b0) { b0 = s0; i0 = c; }
            if (s1 < b1) { b1 = s1; i1 = c; }
        }
        // wave-level lexicographic (s, idx) argmin
#pragma unroll
        for (int off = 1; off < 64; off <<= 1) {
            float os = __shfl_xor(b0, off, 64);
            int   oi = __shfl_xor(i0, off, 64);
            if (os < b0 || (os == b0 && oi < i0)) { b0 = os; i0 = oi; }
            float ps = __shfl_xor(b1, off, 64);
            int   pi = __shfl_xor(i1, off, 64);
            if (ps < b1 || (ps == b1 && pi < i1)) { b1 = ps; i1 = pi; }
        }
        if (lane == 0) {
            rbest[wv] = b0;     rbi[wv] = i0;
            rbest[wv + 4] = b1; rbi[wv + 4] = i1;
        }
        __syncthreads();
        if (tid < 2) {
            float bb = rbest[tid * 4 + 0]; int bi = rbi[tid * 4 + 0];
#pragma unroll
            for (int w = 1; w < 4; ++w) {
                float s = rbest[tid * 4 + w]; int ix = rbi[tid * 4 + w];
                if (s < bb || (s == bb && ix < bi)) { bb = s; bi = ix; }
            }
            fin[tid] = bi;
        }
        __syncthreads();
        int bi0 = fin[0], bi1 = fin[1];
        if (tid < 16)
            ((float4*)(out + (size_t)v0 * DIM))[tid] =
                ((const float4*)(cents + (size_t)bi0 * DIM))[tid];
        else if (tid < 32)
            ((float4*)(out + (size_t)v1 * DIM))[tid - 16] =
                ((const float4*)(cents + (size_t)bi1 * DIM))[tid - 16];
    }
}

extern "C" void kernel_launch(void* const* d_in, const int* in_sizes, int n_in,
                              void* d_out, int out_size, void* d_ws, size_t ws_size,
                              hipStream_t stream) {
    const float* vecs  = (const float*)d_in[0];
    const float* cents = (const float*)d_in[1];
    float*       out   = (float*)d_out;

    // ws layout (16B aligned)
    float*          csq     = (float*)d_ws;                                     //   4096 B
    float*          csq4k   = (float*)((char*)d_ws + 4096);                     //   4096 B
    int*            counter = (int*)((char*)d_ws + 8192);                       //    256 B
    int*            list    = (int*)((char*)d_ws + 16384);                      //   1 MB
    unsigned short* cmat    = (unsigned short*)((char*)d_ws + 16384 + 1048576); // 256 KB

    prep_kernel<<<dim3(64), dim3(256), 0, stream>>>(cents, csq, csq4k, counter, cmat);
    assign_mfma<<<dim3(1024), dim3(256), 0, stream>>>(vecs, cents, cmat, csq4k, out, counter, list);
    rescue_kernel<<<dim3(2048), dim3(256), 0, stream>>>(vecs, cents, csq, counter, list, out);
}

// Round 7
// 224.411 us; speedup vs baseline: 1.9670x; 1.1921x over previous
//
#include <hip/hip_runtime.h>
#include <hip/hip_bf16.h>

#define NVEC   262144
#define NLIST  1024
#define DIM    64
#define NCHUNK 64          // 64 chunks x 16 centroids
#define NGRP   32          // 2 chunks per barrier group
#define SCALE  4096.0f     // int score quantum = 1/4096
#define DELTA_INT 32       // gap threshold in quanta (7.8e-3 in d^2, ~4x worst err)

typedef __attribute__((ext_vector_type(8))) short bf16x8;
typedef __attribute__((ext_vector_type(4))) float f32x4;

__device__ __forceinline__ unsigned short bf_rne(float f) {
    unsigned int u = __float_as_uint(f);
    u += 0x7fffu + ((u >> 16) & 1u);
    return (unsigned short)(u >> 16);
}
__device__ __forceinline__ float bf_up(unsigned short s) {
    return __uint_as_float(((unsigned int)s) << 16);
}

// ---------------------------------------------------------------------------
// K0: csq + csq*SCALE (exact fp32), zero counter, build cmat in FRAG ORDER:
// chunk ch = 4KB image [read r 0..3][lane l][8 shorts]:
//   r=0: hi k 0..31   r=1: hi k 32..63   r=2: lo k 0..31   r=3: lo k 32..63
// assign's ds_read_b128 for read r: lane l reads ch*4096+r*1024+l*16 —
// 64 lanes read a contiguous 1KB; staging order == global_load_lds order.
// ---------------------------------------------------------------------------
__global__ __launch_bounds__(256) void prep_kernel(const float* __restrict__ cents,
                                                   float* __restrict__ csq,
                                                   float* __restrict__ csq4k,
                                                   int* __restrict__ counter,
                                                   unsigned short* __restrict__ cmat) {
    int gid = blockIdx.x * 256 + threadIdx.x;     // 0..16383
    if (gid == 0) *counter = 0;
    if (gid < NLIST) {
        const float4* p = (const float4*)(cents + (size_t)gid * DIM);
        float s = 0.f;
#pragma unroll
        for (int i = 0; i < DIM / 4; ++i) {
            float4 t = p[i];
            s += t.x * t.x + t.y * t.y + t.z * t.z + t.w * t.w;
        }
        csq[gid] = s;
        csq4k[gid] = s * SCALE;
    }
    int c   = gid >> 4;        // centroid 0..1023
    int sub = gid & 15;        // r*4 + q
    int r   = sub >> 2;
    int qq  = sub & 3;
    const float* src = cents + (size_t)c * DIM + (r & 1) * 32 + qq * 8;
    unsigned short* dst = cmat + (c >> 4) * 2048 + r * 512 + (qq * 16 + (c & 15)) * 8;
    bool hi = (r < 2);
#pragma unroll
    for (int i = 0; i < 8; ++i) {
        float v = src[i];
        unsigned short h = bf_rne(v);
        dst[i] = hi ? h : bf_rne(v - bf_up(h));
    }
}

// ---------------------------------------------------------------------------
// K1: MFMA assign + fused gather. 4 waves/block, 2 tiles/wave (32 vecs/wave,
// 128 vecs/block, grid 2048 -> 8192 waves = 32/CU potential). LDS 16.6 KB
// (dbuf 2 chunks/group) -> 9 blocks/CU by LDS. csq read from global (L1-hot).
// dot = c_hi.x_hi + c_lo.x_hi + c_hi.x_lo   (verified math)
// Scores as ints: e = (trunc(SCALE*d2)<<10)|cent -> top-2 via min/max i32.
// ---------------------------------------------------------------------------
__global__ __launch_bounds__(256, 6) void assign_mfma(const float* __restrict__ vecs,
                                                      const float* __restrict__ cents,
                                                      const unsigned short* __restrict__ cmat,
                                                      const float* __restrict__ csq4k,
                                                      float* __restrict__ out,
                                                      int* __restrict__ counter,
                                                      int* __restrict__ list) {
    __shared__ __align__(16) unsigned short chunkbuf[2][2 * 2048];  // 16 KB
    __shared__ unsigned short widx[128];                            // 256 B

    const int tid  = threadIdx.x;
    const int lane = tid & 63;
    const int wave = tid >> 6;
    const int n    = lane & 15;   // vec-in-tile (B / D-col), cent (A-row)
    const int q    = lane >> 4;   // k-group; D-row group

    const int vbase = blockIdx.x * 128 + wave * 32;

    // B fragments: x_hi/x_lo, 2 K-blocks of 32, 2 tiles. 32 VGPRs.
    bf16x8 xhi[2][2], xlo[2][2];
#pragma unroll
    for (int t = 0; t < 2; ++t) {
        const float* vp = vecs + (size_t)(vbase + t * 16 + n) * DIM + q * 8;
#pragma unroll
        for (int kb = 0; kb < 2; ++kb) {
            float4 f0 = *(const float4*)(vp + kb * 32);
            float4 f1 = *(const float4*)(vp + kb * 32 + 4);
            float vv[8] = {f0.x, f0.y, f0.z, f0.w, f1.x, f1.y, f1.z, f1.w};
#pragma unroll
            for (int i = 0; i < 8; ++i) {
                unsigned short h = bf_rne(vv[i]);
                xhi[t][kb][i] = (short)h;
                xlo[t][kb][i] = (short)bf_rne(vv[i] - bf_up(h));
            }
        }
    }

    // stage group 0 (chunks 0,1 = 8 KB = 4 waves x 2 insts x 64 lanes x 16 B)
#pragma unroll
    for (int p = 0; p < 2; ++p) {
        int f  = wave * 2 + p;     // 0..7
        int cc = f >> 2;           // chunk within group
        int r  = f & 3;            // 1KB quarter
        const unsigned short* g = cmat + cc * 2048 + r * 512 + lane * 8;
        __builtin_amdgcn_global_load_lds(
            (const __attribute__((address_space(1))) void*)g,
            (__attribute__((address_space(3))) void*)(&chunkbuf[0][cc * 2048 + r * 512 + lane * 8]),
            16, 0, 0);
    }

    const int IMAX = 0x7FFFFFFF;
    int min1[2] = {IMAX, IMAX};
    int min2[2] = {IMAX, IMAX};

    for (int g = 0; g < NGRP; ++g) {
        __syncthreads();   // publishes buf[g&1]; drains in-flight staging
        if (g + 1 < NGRP) {
#pragma unroll
            for (int p = 0; p < 2; ++p) {
                int f  = wave * 2 + p;
                int cc = f >> 2;
                int r  = f & 3;
                const unsigned short* gp = cmat + ((g + 1) * 2 + cc) * 2048 + r * 512 + lane * 8;
                __builtin_amdgcn_global_load_lds(
                    (const __attribute__((address_space(1))) void*)gp,
                    (__attribute__((address_space(3))) void*)(&chunkbuf[(g + 1) & 1][cc * 2048 + r * 512 + lane * 8]),
                    16, 0, 0);
            }
        }
        const unsigned short* B = chunkbuf[g & 1];
#pragma unroll
        for (int cc2 = 0; cc2 < 2; ++cc2) {
            const int c = g * 2 + cc2;
            const unsigned short* Cb = B + cc2 * 2048 + lane * 8;
            bf16x8 a0 = *(const bf16x8*)(Cb);          // hi, k 0..31
            bf16x8 a1 = *(const bf16x8*)(Cb + 512);    // hi, k 32..63
            bf16x8 a2 = *(const bf16x8*)(Cb + 1024);   // lo, k 0..31
            bf16x8 a3 = *(const bf16x8*)(Cb + 1536);   // lo, k 32..63
            float4 cs = *(const float4*)(csq4k + c * 16 + q * 4);

            f32x4 acc[2];
#pragma unroll
            for (int t = 0; t < 2; ++t) acc[t] = (f32x4){0.f, 0.f, 0.f, 0.f};
            // dot = c_hi.x_hi + c_lo.x_hi + c_hi.x_lo
#pragma unroll
            for (int t = 0; t < 2; ++t) acc[t] = __builtin_amdgcn_mfma_f32_16x16x32_bf16(a0, xhi[t][0], acc[t], 0, 0, 0);
#pragma unroll
            for (int t = 0; t < 2; ++t) acc[t] = __builtin_amdgcn_mfma_f32_16x16x32_bf16(a1, xhi[t][1], acc[t], 0, 0, 0);
#pragma unroll
            for (int t = 0; t < 2; ++t) acc[t] = __builtin_amdgcn_mfma_f32_16x16x32_bf16(a2, xhi[t][0], acc[t], 0, 0, 0);
#pragma unroll
            for (int t = 0; t < 2; ++t) acc[t] = __builtin_amdgcn_mfma_f32_16x16x32_bf16(a3, xhi[t][1], acc[t], 0, 0, 0);
#pragma unroll
            for (int t = 0; t < 2; ++t) acc[t] = __builtin_amdgcn_mfma_f32_16x16x32_bf16(a0, xlo[t][0], acc[t], 0, 0, 0);
#pragma unroll
            for (int t = 0; t < 2; ++t) acc[t] = __builtin_amdgcn_mfma_f32_16x16x32_bf16(a1, xlo[t][1], acc[t], 0, 0, 0);

            const int bg = c * 16 + q * 4;      // + r = centroid index (10 bits)
            float csr[4] = {cs.x, cs.y, cs.z, cs.w};
#pragma unroll
            for (int t = 0; t < 2; ++t) {
#pragma unroll
                for (int r = 0; r < 4; ++r) {
                    float s = fmaf(-2.0f * SCALE, acc[t][r], csr[r]);
                    int qi = (int)s;            // trunc, monotone (s >= 0)
                    int e = (int)((((unsigned)qi) << 10) | (unsigned)(bg + r));
                    min2[t] = min(min2[t], max(min1[t], e));   // old min1!
                    min1[t] = min(min1[t], e);
                }
            }
        }
    }

    // merge top-2 across the 4 quads of each vec-column
#pragma unroll
    for (int t = 0; t < 2; ++t) {
#pragma unroll
        for (int off = 16; off <= 32; off <<= 1) {
            int o1 = __shfl_xor(min1[t], off, 64);
            int o2 = __shfl_xor(min2[t], off, 64);
            int nm2 = min(max(min1[t], o1), min(min2[t], o2));
            min1[t] = min(min1[t], o1);
            min2[t] = nm2;
        }
        if (lane < 16) {
            int slot = wave * 32 + t * 16 + lane;
            widx[slot] = (unsigned short)(min1[t] & 1023);
            if ((min2[t] >> 10) - (min1[t] >> 10) < DELTA_INT) {
                int pos = atomicAdd(counter, 1);
                list[pos] = blockIdx.x * 128 + slot;
            }
        }
    }

    __syncthreads();
    // fused gather: 128 rows x 64 floats, fully coalesced float4 stores
    const size_t obase = (size_t)blockIdx.x * 128;
#pragma unroll
    for (int gI = 0; gI < 8; ++gI) {
        int row = gI * 16 + (tid >> 4);
        int e = tid & 15;
        int idx = widx[row];
        ((float4*)out)[(obase + row) * 16 + e] =
            ((const float4*)cents)[(size_t)idx * 16 + e];
    }
}

// ---------------------------------------------------------------------------
// K2: exact fp32 rescue — block per PAIR of flagged rows; 256 threads,
// thread t dots centroids {t, 256+t, 512+t, 768+t} for both rows (cent row
// loaded once). Exact round-0 fmaf chain; lexicographic (s, idx) reduction.
// ---------------------------------------------------------------------------
__global__ __launch_bounds__(256) void rescue_kernel(const float* __restrict__ vecs,
                                                     const float* __restrict__ cents,
                                                     const float* __restrict__ csq,
                                                     const int* __restrict__ counter,
                                                     const int* __restrict__ list,
                                                     float* __restrict__ out) {
    __shared__ __align__(16) float xs[2][DIM];
    __shared__ float rbest[8];
    __shared__ int   rbi[8];
    __shared__ int   fin[2];

    const int nflag = *counter;
    const int tid  = threadIdx.x;
    const int lane = tid & 63;
    const int wv   = tid >> 6;

    for (int i = blockIdx.x * 2; i < nflag; i += gridDim.x * 2) {
        int v0 = list[i];
        int v1 = (i + 1 < nflag) ? list[i + 1] : v0;
        __syncthreads();
        if (tid < 16)       ((float4*)xs[0])[tid]      = ((const float4*)(vecs + (size_t)v0 * DIM))[tid];
        else if (tid < 32)  ((float4*)xs[1])[tid - 16] = ((const float4*)(vecs + (size_t)v1 * DIM))[tid - 16];
        __syncthreads();

        float b0 = 3.0e38f, b1 = 3.0e38f;
        int   i0 = 0, i1 = 0;
#pragma unroll
        for (int j = 0; j < 4; ++j) {
            int c = j * 256 + tid;              // ascending per thread
            const float4* cp = (const float4*)(cents + (size_t)c * DIM);
            float a0 = 0.f, a1 = 0.f, a2 = 0.f, a3 = 0.f;
            float c0 = 0.f, c1 = 0.f, c2 = 0.f, c3 = 0.f;
#pragma unroll
            for (int k = 0; k < DIM / 4; ++k) {
                float4 cv = cp[k];
                float4 x0 = ((const float4*)xs[0])[k];
                float4 x1 = ((const float4*)xs[1])[k];
                a0 = fmaf(x0.x, cv.x, a0);
                a1 = fmaf(x0.y, cv.y, a1);
                a2 = fmaf(x0.z, cv.z, a2);
                a3 = fmaf(x0.w, cv.w, a3);
                c0 = fmaf(x1.x, cv.x, c0);
                c1 = fmaf(x1.y, cv.y, c1);
                c2 = fmaf(x1.z, cv.z, c2);
                c3 = fmaf(x1.w, cv.w, c3);
            }
            float d0 = (a0 + a1) + (a2 + a3);
            float d1 = (c0 + c1) + (c2 + c3);
            float s0 = fmaf(-2.f, d0, csq[c]);
            float s1 = fmaf(-2.f, d1, csq[c]);
            if (s0 < b0) { b0 = s0; i0 = c; }
            if (s1 < b1) { b1 = s1; i1 = c; }
        }
        // wave-level lexicographic (s, idx) argmin
#pragma unroll
        for (int off = 1; off < 64; off <<= 1) {
            float os = __shfl_xor(b0, off, 64);
            int   oi = __shfl_xor(i0, off, 64);
            if (os < b0 || (os == b0 && oi < i0)) { b0 = os; i0 = oi; }
            float ps = __shfl_xor(b1, off, 64);
            int   pi = __shfl_xor(i1, off, 64);
            if (ps < b1 || (ps == b1 && pi < i1)) { b1 = ps; i1 = pi; }
        }
        if (lane == 0) {
            rbest[wv] = b0;     rbi[wv] = i0;
            rbest[wv + 4] = b1; rbi[wv + 4] = i1;
        }
        __syncthreads();
        if (tid < 2) {
            float bb = rbest[tid * 4 + 0]; int bi = rbi[tid * 4 + 0];
#pragma unroll
            for (int w = 1; w < 4; ++w) {
                float s = rbest[tid * 4 + w]; int ix = rbi[tid * 4 + w];
                if (s < bb || (s == bb && ix < bi)) { bb = s; bi = ix; }
            }
            fin[tid] = bi;
        }
        __syncthreads();
        int bi0 = fin[0], bi1 = fin[1];
        if (tid < 16)
            ((float4*)(out + (size_t)v0 * DIM))[tid] =
                ((const float4*)(cents + (size_t)bi0 * DIM))[tid];
        else if (tid < 32)
            ((float4*)(out + (size_t)v1 * DIM))[tid - 16] =
                ((const float4*)(cents + (size_t)bi1 * DIM))[tid - 16];
    }
}

extern "C" void kernel_launch(void* const* d_in, const int* in_sizes, int n_in,
                              void* d_out, int out_size, void* d_ws, size_t ws_size,
                              hipStream_t stream) {
    const float* vecs  = (const float*)d_in[0];
    const float* cents = (const float*)d_in[1];
    float*       out   = (float*)d_out;

    // ws layout (16B aligned)
    float*          csq     = (float*)d_ws;                                     //   4096 B
    float*          csq4k   = (float*)((char*)d_ws + 4096);                     //   4096 B
    int*            counter = (int*)((char*)d_ws + 8192);                       //    256 B
    int*            list    = (int*)((char*)d_ws + 16384);                      //   1 MB
    unsigned short* cmat    = (unsigned short*)((char*)d_ws + 16384 + 1048576); // 256 KB

    prep_kernel<<<dim3(64), dim3(256), 0, stream>>>(cents, csq, csq4k, counter, cmat);
    assign_mfma<<<dim3(2048), dim3(256), 0, stream>>>(vecs, cents, cmat, csq4k, out, counter, list);
    rescue_kernel<<<dim3(2048), dim3(256), 0, stream>>>(vecs, cents, csq, counter, list, out);
}